// Round 8
// baseline (356.722 us; speedup 1.0000x reference)
//
#include <hip/hip_runtime.h>
#include <hip/hip_cooperative_groups.h>
#include <stdint.h>

namespace cg = cooperative_groups;

// RelationalMSG (R8): 3 dispatches.
//   k_gemm1 : [Ys|Yd] = x@[W1a|W1b] (+b1 on Yd), W1 frags built in-kernel, permuted col layout
//   k_sort  : cooperative: zero cnt + build w2f; hist(dst); per-chunk scan; apply offsets;
//             counting-sort scatter (ssrc grouped by dst). 4 grid.sync()s, register-light.
//   k_agg2  : one 16-node tile per block: CSR aggregate -> LDS (unroll-8, dual chains),
//             barrier, gemm2 from LDS with prebuilt w2f frags loaded AFTER the gather phase.
// Ys/Yd in column-permuted layout pos = c16*8 + ct; inverse baked into w2f.
// N=50000 (=3125*16), E=600000, D=128.

typedef __attribute__((ext_vector_type(8))) short short8;   // 8 bf16 (MFMA A/B frag)
typedef __attribute__((ext_vector_type(4))) float floatx4;  // MFMA C/D frag

#define D 128
#define SPAD 136   // LDS row stride in shorts (272B): <=2-way bank aliasing

static __device__ __forceinline__ unsigned short f2bf(float f) {
    union { float f; unsigned int u; } v; v.f = f;
    unsigned int r = (v.u + 0x7fffu + ((v.u >> 16) & 1u)) >> 16; // RNE
    return (unsigned short)r;
}
static __device__ __forceinline__ float bflo(unsigned int u) {
    union { unsigned int u; float f; } v; v.u = u << 16; return v.f;
}
static __device__ __forceinline__ float bfhi(unsigned int u) {
    union { unsigned int u; float f; } v; v.u = u & 0xffff0000u; return v.f;
}
static __device__ __forceinline__ short8 cvt8(const float* p) {
    float4 f0 = *(const float4*)p;
    float4 f1 = *(const float4*)(p + 4);
    short8 t;
    t[0] = (short)f2bf(f0.x); t[1] = (short)f2bf(f0.y);
    t[2] = (short)f2bf(f0.z); t[3] = (short)f2bf(f0.w);
    t[4] = (short)f2bf(f1.x); t[5] = (short)f2bf(f1.y);
    t[6] = (short)f2bf(f1.z); t[7] = (short)f2bf(f1.w);
    return t;
}

// gemm1: wave w owns out-cols [w*64, w*64+64) of the 256-wide [W1a|W1b].
__global__ __launch_bounds__(256) void k_gemm1(
    const float* __restrict__ x,
    const float* __restrict__ W1,
    const float* __restrict__ b1,
    unsigned short* __restrict__ Ys,
    unsigned short* __restrict__ Yd,
    int N, int nTiles)
{
    const int tid = threadIdx.x, w = tid >> 6, lane = tid & 63;
    const int quad = lane >> 4, col = lane & 15;

    // build this wave's 16 B-fragments from W1 (fp32, L2-resident)
    short8 wf[4][4];
#pragma unroll
    for (int kk = 0; kk < 4; kk++)
#pragma unroll
        for (int j2 = 0; j2 < 4; j2++) {
            int c = (w * 4 + j2) * 16 + col;
            const float* base = (c < 128) ? (W1 + c) : (W1 + 128 * 128 + (c - 128));
            short8 t;
#pragma unroll
            for (int j = 0; j < 8; j++) {
                int k = kk * 32 + quad * 8 + j;
                t[j] = (short)f2bf(base[k * 128]);
            }
            wf[kk][j2] = t;
        }
    float bias[4];
#pragma unroll
    for (int j = 0; j < 4; j++)
        bias[j] = (w >= 2) ? b1[(((w & 1) * 4 + j)) * 16 + col] : 0.f;
    unsigned short* Yhalf = (w < 2) ? Ys : Yd;
    const int ctb = (w & 1) * 4;   // permuted store base: pos = col16*8 + ct

    for (int t = blockIdx.x; t < nTiles; t += gridDim.x) {
        const int n0 = t * 16;
        int nr = n0 + col; if (nr >= N) nr = N - 1;
        floatx4 acc[4];
#pragma unroll
        for (int j = 0; j < 4; j++)
#pragma unroll
            for (int q = 0; q < 4; q++) acc[j][q] = 0.f;
#pragma unroll
        for (int kk = 0; kk < 4; kk++) {
            short8 a = cvt8(x + (long)nr * D + kk * 32 + quad * 8);
#pragma unroll
            for (int j = 0; j < 4; j++)
                acc[j] = __builtin_amdgcn_mfma_f32_16x16x32_bf16(a, wf[kk][j], acc[j], 0, 0, 0);
        }
#pragma unroll
        for (int r = 0; r < 4; r++) {
            int n = n0 + quad * 4 + r;
            if (n < N) {
                ushort4 o;
                o.x = f2bf(acc[0][r] + bias[0]);
                o.y = f2bf(acc[1][r] + bias[1]);
                o.z = f2bf(acc[2][r] + bias[2]);
                o.w = f2bf(acc[3][r] + bias[3]);
                *(ushort4*)(Yhalf + (long)n * D + col * 8 + ctb) = o;
            }
        }
    }
}

// Cooperative sort: zero+w2f | hist | chunk scan | apply | scatter.
__global__ __launch_bounds__(1024) void k_sort(
    const float* __restrict__ W2, unsigned short* __restrict__ w2f,
    const int* __restrict__ esrc, const int* __restrict__ edst,
    int* __restrict__ cnt, int* __restrict__ rowptr, int* __restrict__ cursor,
    int* __restrict__ bsum, int* __restrict__ ssrc,
    int N, int E)
{
    cg::grid_group gg = cg::this_grid();
    const int tid = threadIdx.x, bid = blockIdx.x;
    const int gtid = bid * 1024 + tid;
    const int gsz  = gridDim.x * 1024;
    __shared__ int s[1024];
    __shared__ int boff[64];

    // P0: zero hist + build w2f (layout proven in R5; un-permutes agg cols)
    for (int i = gtid; i < N; i += gsz) cnt[i] = 0;
    for (int t = gtid; t < 32768; t += gsz) {
        int j = t & 7, lane = (t >> 3) & 63, ct = (t >> 9) & 7, kk = t >> 12;
        int k = kk * 32 + (lane >> 4) * 8 + j;
        int c = ct * 16 + (lane & 15);
        int row = (k < 128) ? k : (128 + ((k - 128) & 7) * 16 + ((k - 128) >> 3));
        w2f[t] = f2bf(W2[row * 128 + c]);
    }
    gg.sync();

    // P1: histogram
    for (int i = gtid; i < E; i += gsz) atomicAdd(&cnt[edst[i]], 1);
    gg.sync();

    // P2: per-1024-chunk exclusive scan (blocks 0..nChunk-1)
    const int nChunk = (N + 1023) >> 10;   // 49
    if (bid < nChunk) {
        int i = bid * 1024 + tid;
        int c = (i < N) ? cnt[i] : 0;
        s[tid] = c; __syncthreads();
        for (int off = 1; off < 1024; off <<= 1) {
            int t2 = (tid >= off) ? s[tid - off] : 0;
            __syncthreads();
            s[tid] += t2;
            __syncthreads();
        }
        if (i < N) rowptr[i] = s[tid] - c;
        if (tid == 1023) bsum[bid] = s[1023];
    }
    gg.sync();

    // P3: chunk-offset scan (redundant per block) + apply
    if (tid < 64) {
        int v = (tid < nChunk) ? bsum[tid] : 0;
        int incl = v;
        for (int o = 1; o < 64; o <<= 1) {
            int t2 = __shfl_up(incl, o, 64);
            if (tid >= o) incl += t2;
        }
        boff[tid] = incl - v;
    }
    __syncthreads();
    for (int i = gtid; i < N; i += gsz) {
        int r = rowptr[i] + boff[i >> 10];
        rowptr[i] = r;
        cursor[i] = r;
    }
    if (gtid == 0) rowptr[N] = E;
    gg.sync();

    // P4: counting-sort scatter
    for (int i = gtid; i < E; i += gsz) {
        int p = atomicAdd(&cursor[edst[i]], 1);
        ssrc[p] = esrc[i];
    }
}

// Fused CSR-aggregate + gemm2, ONE 16-node tile per block.
__global__ __launch_bounds__(256) void k_agg2(
    const float* __restrict__ x,
    const unsigned short* __restrict__ w2f,
    const float* __restrict__ b2,
    const unsigned short* __restrict__ Ys,
    const unsigned short* __restrict__ Yd,
    const int* __restrict__ rowptr,
    const int* __restrict__ ssrc,
    float* __restrict__ out,
    int N)
{
    __shared__ unsigned short sagg[16][SPAD];
    const int tid = threadIdx.x, w = tid >> 6, lane = tid & 63;
    const int quad = lane >> 4, col = lane & 15;
    const int n0 = blockIdx.x * 16;

    // ---- Phase A: wave w aggregates nodes n0+w*4..+3 into LDS (permuted cols) ----
#pragma unroll
    for (int i = 0; i < 4; i++) {
        int n = n0 + w * 4 + i;
        if (n < N) {
            int rp0 = rowptr[n], rp1 = rowptr[n + 1];
            unsigned int ydu = *(const unsigned int*)(Yd + (long)n * D + lane * 2);
            float yd0 = bflo(ydu), yd1 = bfhi(ydu);
            float a0 = 0.f, a1 = 0.f, c0 = 0.f, c1 = 0.f;
            int e = rp0;
            for (; e + 8 <= rp1; e += 8) {
                int s0 = ssrc[e],     s1 = ssrc[e + 1], s2 = ssrc[e + 2], s3 = ssrc[e + 3];
                int s4 = ssrc[e + 4], s5 = ssrc[e + 5], s6 = ssrc[e + 6], s7 = ssrc[e + 7];
                unsigned int u0 = *(const unsigned int*)(Ys + (long)s0 * D + lane * 2);
                unsigned int u1 = *(const unsigned int*)(Ys + (long)s1 * D + lane * 2);
                unsigned int u2 = *(const unsigned int*)(Ys + (long)s2 * D + lane * 2);
                unsigned int u3 = *(const unsigned int*)(Ys + (long)s3 * D + lane * 2);
                unsigned int u4 = *(const unsigned int*)(Ys + (long)s4 * D + lane * 2);
                unsigned int u5 = *(const unsigned int*)(Ys + (long)s5 * D + lane * 2);
                unsigned int u6 = *(const unsigned int*)(Ys + (long)s6 * D + lane * 2);
                unsigned int u7 = *(const unsigned int*)(Ys + (long)s7 * D + lane * 2);
                a0 += fmaxf(bflo(u0) + yd0, 0.f); a1 += fmaxf(bfhi(u0) + yd1, 0.f);
                a0 += fmaxf(bflo(u1) + yd0, 0.f); a1 += fmaxf(bfhi(u1) + yd1, 0.f);
                a0 += fmaxf(bflo(u2) + yd0, 0.f); a1 += fmaxf(bfhi(u2) + yd1, 0.f);
                a0 += fmaxf(bflo(u3) + yd0, 0.f); a1 += fmaxf(bfhi(u3) + yd1, 0.f);
                c0 += fmaxf(bflo(u4) + yd0, 0.f); c1 += fmaxf(bfhi(u4) + yd1, 0.f);
                c0 += fmaxf(bflo(u5) + yd0, 0.f); c1 += fmaxf(bfhi(u5) + yd1, 0.f);
                c0 += fmaxf(bflo(u6) + yd0, 0.f); c1 += fmaxf(bfhi(u6) + yd1, 0.f);
                c0 += fmaxf(bflo(u7) + yd0, 0.f); c1 += fmaxf(bfhi(u7) + yd1, 0.f);
            }
            for (; e < rp1; e++) {
                int s0 = ssrc[e];
                unsigned int u0 = *(const unsigned int*)(Ys + (long)s0 * D + lane * 2);
                a0 += fmaxf(bflo(u0) + yd0, 0.f); a1 += fmaxf(bfhi(u0) + yd1, 0.f);
            }
            a0 += c0; a1 += c1;
            unsigned int o = (unsigned int)f2bf(a0) | ((unsigned int)f2bf(a1) << 16);
            *(unsigned int*)&sagg[w * 4 + i][lane * 2] = o;
        }
    }
    __syncthreads();

    // ---- Phase B: gemm2 on the tile (wf loaded AFTER gather to keep Phase A lean) ----
    short8 wf[8][2];
#pragma unroll
    for (int kk = 0; kk < 8; kk++)
#pragma unroll
        for (int c2 = 0; c2 < 2; c2++)
            wf[kk][c2] = ((const short8*)w2f)[(kk * 8 + w * 2 + c2) * 64 + lane];
    float bias[2];
    bias[0] = b2[(w * 2) * 16 + col];
    bias[1] = b2[(w * 2 + 1) * 16 + col];

    int nr = n0 + col; if (nr >= N) nr = N - 1;
    floatx4 acc[2];
#pragma unroll
    for (int c = 0; c < 2; c++)
#pragma unroll
        for (int q = 0; q < 4; q++) acc[c][q] = 0.f;
#pragma unroll
    for (int kk = 0; kk < 8; kk++) {
        short8 a;
        if (kk < 4)
            a = cvt8(x + (long)nr * D + kk * 32 + quad * 8);
        else
            a = *(const short8*)&sagg[col][(kk - 4) * 32 + quad * 8];
        acc[0] = __builtin_amdgcn_mfma_f32_16x16x32_bf16(a, wf[kk][0], acc[0], 0, 0, 0);
        acc[1] = __builtin_amdgcn_mfma_f32_16x16x32_bf16(a, wf[kk][1], acc[1], 0, 0, 0);
    }
#pragma unroll
    for (int c = 0; c < 2; c++)
#pragma unroll
        for (int r = 0; r < 4; r++) {
            int n = n0 + quad * 4 + r;
            if (n < N) {
                long idx = (long)n * D + (w * 2 + c) * 16 + col;
                float v = acc[c][r] + bias[c];
                v = v > 0.f ? v : 0.f;
                out[idx] = x[idx] + v;
            }
        }
}

// ---- fallback pieces (non-cooperative), in case coop launch is rejected ----
__global__ void k_zero_hist(const float* __restrict__ W2, unsigned short* __restrict__ w2f,
                            const int* __restrict__ edst, int* __restrict__ cnt, int N, int E) {
    int gid = blockIdx.x * blockDim.x + threadIdx.x;
    if (gid < N) cnt[gid] = 0;
    if (gid < 32768) {
        int t = gid;
        int j = t & 7, lane = (t >> 3) & 63, ct = (t >> 9) & 7, kk = t >> 12;
        int k = kk * 32 + (lane >> 4) * 8 + j;
        int c = ct * 16 + (lane & 15);
        int row = (k < 128) ? k : (128 + ((k - 128) & 7) * 16 + ((k - 128) >> 3));
        w2f[t] = f2bf(W2[row * 128 + c]);
    }
}
__global__ void k_hist(const int* __restrict__ dst, int* __restrict__ cnt, int E) {
    int i = blockIdx.x * blockDim.x + threadIdx.x;
    if (i < E) atomicAdd(&cnt[dst[i]], 1);
}
__global__ __launch_bounds__(1024) void k_scanA(const int* __restrict__ cnt,
                                                int* __restrict__ rowptr,
                                                int* __restrict__ bsum, int N) {
    __shared__ int s[1024];
    int tid = threadIdx.x, i = blockIdx.x * 1024 + tid;
    int c = (i < N) ? cnt[i] : 0;
    s[tid] = c; __syncthreads();
    for (int off = 1; off < 1024; off <<= 1) {
        int t = (tid >= off) ? s[tid - off] : 0;
        __syncthreads();
        s[tid] += t;
        __syncthreads();
    }
    if (i < N) rowptr[i] = s[tid] - c;
    if (tid == 1023) bsum[blockIdx.x] = s[1023];
}
__global__ __launch_bounds__(1024) void k_scanBC(int* __restrict__ rowptr,
                                                 int* __restrict__ cursor,
                                                 const int* __restrict__ bsum,
                                                 int N, int E, int nChunk) {
    __shared__ int off;
    const int tid = threadIdx.x;
    if (tid < 64) {
        int v = (tid < nChunk) ? bsum[tid] : 0;
        int incl = v;
        for (int o = 1; o < 64; o <<= 1) {
            int t = __shfl_up(incl, o, 64);
            if (tid >= o) incl += t;
        }
        if (tid == blockIdx.x) off = incl - v;
    }
    __syncthreads();
    int i = blockIdx.x * 1024 + tid;
    if (i < N) {
        int r = rowptr[i] + off;
        rowptr[i] = r;
        cursor[i] = r;
    }
    if (i == 0) rowptr[N] = E;
}
__global__ void k_scatter(const int* __restrict__ src, const int* __restrict__ dst,
                          int* __restrict__ cursor, int* __restrict__ ssrc, int E) {
    int i = blockIdx.x * blockDim.x + threadIdx.x;
    if (i < E) {
        int p = atomicAdd(&cursor[dst[i]], 1);
        ssrc[p] = src[i];
    }
}

extern "C" void kernel_launch(void* const* d_in, const int* in_sizes, int n_in,
                              void* d_out, int out_size, void* d_ws, size_t ws_size,
                              hipStream_t stream)
{
    const float* x   = (const float*)d_in[0];
    const int* esrc  = (const int*)d_in[1];
    const int* edst  = (const int*)d_in[2];
    const float* W1  = (const float*)d_in[3];
    const float* b1  = (const float*)d_in[4];
    const float* W2  = (const float*)d_in[5];
    const float* b2  = (const float*)d_in[6];
    float* out = (float*)d_out;

    const int ND = in_sizes[0];     // N*D
    int N = ND / D;                 // 50000
    int E = in_sizes[1];            // 600000

    // workspace carve-out (256B-aligned), ~29 MB
    char* p = (char*)d_ws;
    auto alloc = [&](size_t bytes) { char* r = p; p += (bytes + 255) & ~(size_t)255; return r; };
    unsigned short* Ys  = (unsigned short*)alloc((size_t)ND * 2);
    unsigned short* Yd  = (unsigned short*)alloc((size_t)ND * 2);
    unsigned short* w2f = (unsigned short*)alloc(32768 * 2);
    int* rowptr = (int*)alloc((size_t)(N + 1) * 4);
    int* cursor = (int*)alloc((size_t)N * 4);
    int* cnt    = (int*)alloc((size_t)N * 4);
    int* bsum   = (int*)alloc(64 * 4);
    int* ssrc   = (int*)alloc((size_t)E * 4);

    const int nTiles = (N + 15) / 16;     // 3125

    k_gemm1<<<1024, 256, 0, stream>>>(x, W1, b1, Ys, Yd, N, nTiles);

    void* args[] = {
        (void*)&W2, (void*)&w2f, (void*)&esrc, (void*)&edst,
        (void*)&cnt, (void*)&rowptr, (void*)&cursor, (void*)&bsum, (void*)&ssrc,
        (void*)&N, (void*)&E
    };
    hipError_t le = hipLaunchCooperativeKernel((const void*)k_sort, dim3(256), dim3(1024),
                                               args, 0, stream);
    if (le != hipSuccess) {
        const int nChunk = (N + 1023) / 1024;
        k_zero_hist<<<(N + 255) / 256, 256, 0, stream>>>(W2, w2f, edst, cnt, N, E);
        k_hist<<<(E + 255) / 256, 256, 0, stream>>>(edst, cnt, E);
        k_scanA<<<nChunk, 1024, 0, stream>>>(cnt, rowptr, bsum, N);
        k_scanBC<<<nChunk, 1024, 0, stream>>>(rowptr, cursor, bsum, N, E, nChunk);
        k_scatter<<<(E + 255) / 256, 256, 0, stream>>>(esrc, edst, cursor, ssrc, E);
    }

    k_agg2<<<nTiles, 256, 0, stream>>>(x, w2f, b2, Ys, Yd, rowptr, ssrc, out, N);
}